// Round 1
// baseline (7432.793 us; speedup 1.0000x reference)
//
#include <hip/hip_runtime.h>

typedef __attribute__((ext_vector_type(4))) float f32x4;
typedef __attribute__((ext_vector_type(8))) short bf16x8;

#define DEV __device__ __forceinline__

DEV float b2f(ushort u) { return __uint_as_float(((uint)u) << 16); }
DEV ushort f2b(float f) {
    uint u = __float_as_uint(f);
    return (ushort)((u + 0x7fffu + ((u >> 16) & 1u)) >> 16);  // RNE
}
DEV float fsig(float x) {
    x = fminf(fmaxf(x, -30.f), 30.f);
    return 1.f / (1.f + __expf(-x));
}
DEV float ftanh(float x) {
    x = fminf(fmaxf(x, -15.f), 15.f);
    float e = __expf(2.f * x);
    return (e - 1.f) / (e + 1.f);
}
DEV void gload_lds16(const void* g, void* l) {
    __builtin_amdgcn_global_load_lds(
        (const __attribute__((address_space(1))) void*)g,
        (__attribute__((address_space(3))) void*)l, 16, 0, 0);
}

// ---------------- f32 -> bf16 weight conversion ----------------
__global__ void f2b_kernel(const float* __restrict__ s, ushort* __restrict__ d, int n) {
    int i = blockIdx.x * 256 + threadIdx.x;
    if (i < n) d[i] = f2b(s[i]);
}

// ---------------- embedding gather -> x0 [S][B][E] bf16 ----------------
// grid 65536 (= S*B rows, row = t*512+b), block 256 (= E)
__global__ void embed_kernel(const int* __restrict__ tok, const float* __restrict__ emb,
                             ushort* __restrict__ x0) {
    int row = blockIdx.x;
    int t = row >> 9, b = row & 511;
    int tk = tok[b * 128 + t];
    x0[(size_t)row * 256 + threadIdx.x] = f2b(emb[(size_t)tk * 256 + threadIdx.x]);
}

// ---------------- bf16 NT GEMM (m97-style): C[m][n] = A[m][:]·Bw[n][:] + bias ----------------
// A [M][K] bf16, Bw [N][K] bf16, C [M][N] bf16. BM=BN=128, BK=32, 4 waves (2x2), 64x64/wave.
__global__ __launch_bounds__(256) void gemm_bias_kernel(
    const ushort* __restrict__ A, const ushort* __restrict__ Bw,
    const float* __restrict__ bias0, const float* __restrict__ bias1,
    ushort* __restrict__ C, int M, int N, int K) {
    __shared__ ushort la[128 * 32];
    __shared__ ushort lb[128 * 32];
    const int tid = threadIdx.x;
    const int wave = tid >> 6, lane = tid & 63;
    const int ntn = N >> 7;
    const int tm = blockIdx.x / ntn, tn = blockIdx.x % ntn;
    const int m0 = tm << 7, n0 = tn << 7;
    const int wm = (wave >> 1) * 64, wn = (wave & 1) * 64;
    f32x4 acc[4][4] = {};
    const int nks = K >> 5;
    const int srow = tid >> 2, scol = (tid & 3) * 8;
    for (int ks = 0; ks < nks; ++ks) {
        const int k0 = ks << 5;
#pragma unroll
        for (int r = 0; r < 2; ++r) {
            gload_lds16(A + (size_t)(m0 + r * 64 + srow) * K + k0 + scol, &la[r * 2048 + wave * 512]);
            gload_lds16(Bw + (size_t)(n0 + r * 64 + srow) * K + k0 + scol, &lb[r * 2048 + wave * 512]);
        }
        __syncthreads();
        bf16x8 af[4], bfr[4];
#pragma unroll
        for (int i = 0; i < 4; ++i)
            af[i] = *(const bf16x8*)&la[(wm + i * 16 + (lane & 15)) * 32 + (lane >> 4) * 8];
#pragma unroll
        for (int i = 0; i < 4; ++i)
            bfr[i] = *(const bf16x8*)&lb[(wn + i * 16 + (lane & 15)) * 32 + (lane >> 4) * 8];
#pragma unroll
        for (int mi = 0; mi < 4; ++mi)
#pragma unroll
            for (int ni = 0; ni < 4; ++ni)
                acc[mi][ni] = __builtin_amdgcn_mfma_f32_16x16x32_bf16(af[mi], bfr[ni], acc[mi][ni], 0, 0, 0);
        __syncthreads();
    }
#pragma unroll
    for (int mi = 0; mi < 4; ++mi) {
        int row = m0 + wm + mi * 16 + ((lane >> 4) << 2);
#pragma unroll
        for (int j = 0; j < 4; ++j) {
#pragma unroll
            for (int ni = 0; ni < 4; ++ni) {
                int col = n0 + wn + ni * 16 + (lane & 15);
                C[(size_t)(row + j) * N + col] = f2b(acc[mi][ni][j] + bias0[col] + bias1[col]);
            }
        }
    }
}

// ---------------- fused LSTM step: gates = xproj[t] + h_{t-1} @ Whh^T ; elementwise ----------------
// grid 256 = 8 btiles(64) x 32 htiles(16); block 256 (4 waves; wave g computes gate g's 64x16)
__global__ __launch_bounds__(256) void lstm_step_kernel(
    const ushort* __restrict__ xproj_t,  // [512][2048] bf16
    const ushort* __restrict__ Whh,      // [2048][512] bf16
    const ushort* __restrict__ hprev,    // [512][512] bf16 (t-1), unused at t==0
    ushort* __restrict__ hout,           // [512][512] bf16 (t)
    float* __restrict__ cstate,          // [512][512] f32
    float* __restrict__ hT, float* __restrict__ cT,
    int t) {
    union SmU {
        struct { ushort a[64 * 32]; ushort b[64 * 32]; } st;
        float g[4][64][16];
    };
    __shared__ SmU sm;
    const int tid = threadIdx.x;
    const int wave = tid >> 6, lane = tid & 63;
    const int b0 = (blockIdx.x >> 5) << 6;
    const int h0 = (blockIdx.x & 31) << 4;
    f32x4 acc[4] = {};
    if (t > 0) {
        const ushort* Ab = hprev + (size_t)b0 * 512;
        const ushort* Bb = Whh + ((size_t)wave * 512 + h0) * 512;
        const int arow = tid >> 2, acol = (tid & 3) * 8;
        const int brow = lane >> 2, bcol = (lane & 3) * 8;
        for (int ks = 0; ks < 16; ++ks) {
            const int k0 = ks << 5;
            gload_lds16(Ab + (size_t)arow * 512 + k0 + acol, &sm.st.a[wave * 512]);
            gload_lds16(Bb + (size_t)brow * 512 + k0 + bcol, &sm.st.b[wave * 512]);
            __syncthreads();
            bf16x8 bfr = *(const bf16x8*)&sm.st.b[wave * 512 + (lane & 15) * 32 + (lane >> 4) * 8];
#pragma unroll
            for (int mi = 0; mi < 4; ++mi) {
                bf16x8 af = *(const bf16x8*)&sm.st.a[(mi * 16 + (lane & 15)) * 32 + (lane >> 4) * 8];
                acc[mi] = __builtin_amdgcn_mfma_f32_16x16x32_bf16(af, bfr, acc[mi], 0, 0, 0);
            }
            __syncthreads();
        }
    }
#pragma unroll
    for (int mi = 0; mi < 4; ++mi) {
        int row = mi * 16 + ((lane >> 4) << 2);
#pragma unroll
        for (int j = 0; j < 4; ++j) sm.g[wave][row + j][lane & 15] = acc[mi][j];
    }
    __syncthreads();
#pragma unroll
    for (int i = 0; i < 4; ++i) {
        int e = i * 256 + tid;
        int b = e >> 4, hh = e & 15;
        size_t xb = (size_t)(b0 + b) * 2048 + h0 + hh;
        float gi = sm.g[0][b][hh] + b2f(xproj_t[xb]);
        float gf = sm.g[1][b][hh] + b2f(xproj_t[xb + 512]);
        float gg = sm.g[2][b][hh] + b2f(xproj_t[xb + 1024]);
        float go = sm.g[3][b][hh] + b2f(xproj_t[xb + 1536]);
        float ig = fsig(gi), fg = fsig(gf), gv = ftanh(gg), og = fsig(go);
        size_t ci = (size_t)(b0 + b) * 512 + h0 + hh;
        float cp = (t > 0) ? cstate[ci] : 0.f;
        float cn = fg * cp + ig * gv;
        float hn = og * ftanh(cn);
        cstate[ci] = cn;
        hout[ci] = f2b(hn);
        if (t == 127) { hT[ci] = hn; cT[ci] = cn; }
    }
}

// ---------------- output projection: logits[b][t][v] = hs[t][b][:]·Wout[v][:] + bout[v] ----------------
// grid 2048 (32 rows each), block 256: rg=tid&7 -> 4 rows, vg=tid>>3 -> v, v+32
__global__ __launch_bounds__(256) void outproj_kernel(
    const ushort* __restrict__ hs, const float* __restrict__ Wout,
    const float* __restrict__ bout, float* __restrict__ out) {
    __shared__ ushort lh[32 * 512];
    const int tid = threadIdx.x;
    const size_t r0 = (size_t)blockIdx.x * 32;
    const uint4* gs = (const uint4*)(hs + r0 * 512);
    uint4* ls = (uint4*)lh;
    for (int i = tid; i < 2048; i += 256) ls[i] = gs[i];
    __syncthreads();
    const int rg = tid & 7, vg = tid >> 3;
    float acc[4][2] = {};
    for (int k8 = 0; k8 < 64; ++k8) {
        float hf[4][8];
#pragma unroll
        for (int rr = 0; rr < 4; ++rr) {
            bf16x8 hv = *(const bf16x8*)&lh[(rg * 4 + rr) * 512 + k8 * 8];
#pragma unroll
            for (int j = 0; j < 8; ++j) hf[rr][j] = b2f((ushort)hv[j]);
        }
#pragma unroll
        for (int vi = 0; vi < 2; ++vi) {
            int v = vg + vi * 32;
            if (v < 37) {
                const float* wp = Wout + (size_t)v * 512 + k8 * 8;
                float4 w0 = *(const float4*)wp;
                float4 w1 = *(const float4*)(wp + 4);
                float wv[8] = {w0.x, w0.y, w0.z, w0.w, w1.x, w1.y, w1.z, w1.w};
#pragma unroll
                for (int rr = 0; rr < 4; ++rr) {
                    float s = 0.f;
#pragma unroll
                    for (int j = 0; j < 8; ++j) s += hf[rr][j] * wv[j];
                    acc[rr][vi] += s;
                }
            }
        }
    }
#pragma unroll
    for (int vi = 0; vi < 2; ++vi) {
        int v = vg + vi * 32;
        if (v < 37) {
#pragma unroll
            for (int rr = 0; rr < 4; ++rr) {
                size_t r = r0 + rg * 4 + rr;
                int t = (int)(r >> 9), b = (int)(r & 511);
                out[((size_t)b * 128 + t) * 37 + v] = acc[rr][vi] + bout[v];
            }
        }
    }
}

extern "C" void kernel_launch(void* const* d_in, const int* in_sizes, int n_in,
                              void* d_out, int out_size, void* d_ws, size_t ws_size,
                              hipStream_t stream) {
    (void)in_sizes; (void)n_in; (void)out_size; (void)ws_size;
    const int* tokens = (const int*)d_in[0];
    const float* emb = (const float*)d_in[1];
    const float* Wih_f[3] = {(const float*)d_in[2], (const float*)d_in[6], (const float*)d_in[10]};
    const float* Whh_f[3] = {(const float*)d_in[3], (const float*)d_in[7], (const float*)d_in[11]};
    const float* bih[3] = {(const float*)d_in[4], (const float*)d_in[8], (const float*)d_in[12]};
    const float* bhh[3] = {(const float*)d_in[5], (const float*)d_in[9], (const float*)d_in[13]};
    const float* Wout = (const float*)d_in[14];
    const float* bout = (const float*)d_in[15];
    float* out = (float*)d_out;

    char* ws = (char*)d_ws;
    size_t off = 0;
    auto take = [&](size_t nb) -> void* {
        void* p = ws + off;
        off = (off + nb + 255) & ~(size_t)255;
        return p;
    };
    ushort* x0 = (ushort*)take((size_t)128 * 512 * 256 * 2);   // 16MB  [S][B][E]
    ushort* hsA = (ushort*)take((size_t)128 * 512 * 512 * 2);  // 64MB  [S][B][H]
    ushort* hsB = (ushort*)take((size_t)128 * 512 * 512 * 2);  // 64MB
    ushort* xpj = (ushort*)take((size_t)32 * 512 * 2048 * 2);  // 64MB  chunk [32][B][4H]
    float* cst = (float*)take((size_t)512 * 512 * 4);          // 1MB
    ushort* wih[3];
    wih[0] = (ushort*)take((size_t)2048 * 256 * 2);
    wih[1] = (ushort*)take((size_t)2048 * 512 * 2);
    wih[2] = (ushort*)take((size_t)2048 * 512 * 2);
    ushort* whh[3];
    for (int l = 0; l < 3; ++l) whh[l] = (ushort*)take((size_t)2048 * 512 * 2);

    // weight conversion to bf16
    f2b_kernel<<<2048, 256, 0, stream>>>(Wih_f[0], wih[0], 2048 * 256);
    f2b_kernel<<<4096, 256, 0, stream>>>(Wih_f[1], wih[1], 2048 * 512);
    f2b_kernel<<<4096, 256, 0, stream>>>(Wih_f[2], wih[2], 2048 * 512);
    for (int l = 0; l < 3; ++l)
        f2b_kernel<<<4096, 256, 0, stream>>>(Whh_f[l], whh[l], 2048 * 512);

    embed_kernel<<<65536, 256, 0, stream>>>(tokens, emb, x0);

    float* hTbase = out + 2424832;
    float* cTbase = out + 2424832 + 786432;
    const ushort* src = x0;
    ushort* hs_out = hsA;
    for (int l = 0; l < 3; ++l) {
        int K = (l == 0) ? 256 : 512;
        hs_out = (l == 1) ? hsB : hsA;
        for (int ch = 0; ch < 4; ++ch) {
            gemm_bias_kernel<<<2048, 256, 0, stream>>>(
                src + (size_t)ch * 16384 * K, wih[l], bih[l], bhh[l], xpj, 16384, 2048, K);
            for (int tt = 0; tt < 32; ++tt) {
                int t = ch * 32 + tt;
                lstm_step_kernel<<<256, 256, 0, stream>>>(
                    xpj + (size_t)tt * 512 * 2048, whh[l],
                    hs_out + (size_t)(t > 0 ? t - 1 : 0) * 512 * 512,
                    hs_out + (size_t)t * 512 * 512,
                    cst, hTbase + (size_t)l * 262144, cTbase + (size_t)l * 262144, t);
            }
        }
        src = hs_out;
    }
    outproj_kernel<<<2048, 256, 0, stream>>>(hs_out, Wout, bout, out);
}